// Round 12
// baseline (564.147 us; speedup 1.0000x reference)
//
#include <hip/hip_runtime.h>
#include <hip/hip_bf16.h>

#define N_NODES 50000
#define DIM 128
#define N_GRAPHS 64
#define E_RAW 800000
#define E_TOT 850000
#define E_CAP 1200000   // >= E_TOT + 3*N_NODES (pad-to-4) + slack
#define NEG_SLOPE 0.2f

typedef unsigned int uint;
typedef unsigned short ushort;
typedef float v2f __attribute__((ext_vector_type(2)));

// ---------- init: counters + pooled only ----------
__global__ void init_kernel(int* deg, int* fillc, float* pooled) {
    int i = blockIdx.x * blockDim.x + threadIdx.x;
    if (i < N_NODES) { deg[i] = 0; fillc[i] = 0; }
    if (i < N_GRAPHS * DIM) pooled[i] = 0.f;
}

// ---------- CSR build (dst-sorted, segments padded to multiple of 4) ----------
__global__ void count_kernel(const int* __restrict__ ei, int* __restrict__ deg) {
    int e = blockIdx.x * blockDim.x + threadIdx.x;
    if (e >= E_TOT) return;
    int dst = (e < E_RAW) ? ei[E_RAW + e] : (e - E_RAW);
    atomicAdd(&deg[dst], 1);
}

__global__ void scan1_kernel(const int* __restrict__ deg, int* __restrict__ excl,
                             int* __restrict__ blksum, int n) {
    __shared__ int lds[256];
    int t = threadIdx.x;
    int i = blockIdx.x * 256 + t;
    int v = (i < n) ? ((deg[i] + 3) & ~3) : 0;   // pad degree to multiple of 4
    lds[t] = v;
    __syncthreads();
    int incl = v;
    for (int off = 1; off < 256; off <<= 1) {
        int y = (t >= off) ? lds[t - off] : 0;
        __syncthreads();
        incl += y;
        lds[t] = incl;
        __syncthreads();
    }
    if (i < n) excl[i] = incl - v;
    if (t == 255) blksum[blockIdx.x] = incl;
}

__global__ void scan2_kernel(int* __restrict__ blksum, int* __restrict__ row_ptr, int nblk) {
    __shared__ int lds[256];
    int t = threadIdx.x;
    int v = (t < nblk) ? blksum[t] : 0;
    lds[t] = v;
    __syncthreads();
    int incl = v;
    for (int off = 1; off < 256; off <<= 1) {
        int y = (t >= off) ? lds[t - off] : 0;
        __syncthreads();
        incl += y;
        lds[t] = incl;
        __syncthreads();
    }
    if (t < nblk) blksum[t] = incl - v;
    if (t == nblk - 1) row_ptr[N_NODES] = incl;
}

__global__ void scan3_kernel(int* __restrict__ row_ptr, const int* __restrict__ blksum, int n) {
    int i = blockIdx.x * blockDim.x + threadIdx.x;
    if (i < n) row_ptr[i] += blksum[i >> 8];
}

// write -1 into the <=3 pad slots of each node's segment
__global__ void pad_kernel(const int* __restrict__ deg, const int* __restrict__ row_ptr,
                           int* __restrict__ csr_src) {
    int i = blockIdx.x * blockDim.x + threadIdx.x;
    if (i >= N_NODES) return;
    int d = deg[i];
    int pd = (d + 3) & ~3;
    int base = row_ptr[i];
    for (int k = d; k < pd; ++k) csr_src[base + k] = -1;
}

__global__ void fill_kernel(const int* __restrict__ ei, const int* __restrict__ row_ptr,
                            int* __restrict__ fillc, int* __restrict__ csr_src) {
    int e = blockIdx.x * blockDim.x + threadIdx.x;
    if (e >= E_TOT) return;
    int src, dst;
    if (e < E_RAW) { src = ei[e]; dst = ei[E_RAW + e]; }
    else           { src = dst = e - E_RAW; }
    int slot = row_ptr[dst] + atomicAdd(&fillc[dst], 1);
    csr_src[slot] = src;
}

// ---------- GEMM + fused attention dots; H written as packed fp8 e4m3 ----------
// W staged through LDS in 32-row chunks (16 KiB -> ~5 blocks/CU vs 2 with the
// old 64 KiB buffer). Lane tx owns cols {tx*4..+3, 64+tx*4..+3}: LDS reads are
// float4 at word addr tx*4 -> 2 lanes/bank = conflict-free (vs 4-way before).
// Packed-fp8 byte layout is unchanged (byte index == column), so agg is as-is.
__global__ __launch_bounds__(256) void gemm_dots_kernel(
    const float* __restrict__ X, const float* __restrict__ W,
    const float* __restrict__ asrc, const float* __restrict__ adst,
    uint* __restrict__ Hb, float* __restrict__ s1, float* __restrict__ s2, int nrows) {
    __shared__ float Wl[32][DIM];   // 16 KiB chunk
    int t = threadIdx.x;
    int tx = t & 15, ty = t >> 4;
    int row0 = blockIdx.x * 64 + ty * 4;
    int cA = tx * 4;        // columns cA..cA+3
    int cB = 64 + tx * 4;   // columns cB..cB+3

    float acc[4][8];
#pragma unroll
    for (int r = 0; r < 4; ++r)
#pragma unroll
        for (int c = 0; c < 8; ++c) acc[r][c] = 0.f;

    for (int k0 = 0; k0 < DIM; k0 += 32) {
        // load W[k0..k0+32) x 128 = 4096 floats; 256 threads x 4 float4
        for (int i = t; i < 32 * DIM / 4; i += 256)
            ((float4*)&Wl[0][0])[i] = ((const float4*)&W[k0 * DIM])[i];
        __syncthreads();

        for (int kk = 0; kk < 32; kk += 4) {
            float4 xr[4];
#pragma unroll
            for (int r = 0; r < 4; ++r) {
                int row = row0 + r;
                xr[r] = (row < nrows) ? *(const float4*)&X[(size_t)row * DIM + k0 + kk]
                                      : make_float4(0.f, 0.f, 0.f, 0.f);
            }
#pragma unroll
            for (int kj = 0; kj < 4; ++kj) {
                float4 wA = *(const float4*)&Wl[kk + kj][cA];
                float4 wB = *(const float4*)&Wl[kk + kj][cB];
#pragma unroll
                for (int r = 0; r < 4; ++r) {
                    float xv = (kj == 0) ? xr[r].x : (kj == 1) ? xr[r].y
                             : (kj == 2) ? xr[r].z : xr[r].w;
                    acc[r][0] = fmaf(xv, wA.x, acc[r][0]);
                    acc[r][1] = fmaf(xv, wA.y, acc[r][1]);
                    acc[r][2] = fmaf(xv, wA.z, acc[r][2]);
                    acc[r][3] = fmaf(xv, wA.w, acc[r][3]);
                    acc[r][4] = fmaf(xv, wB.x, acc[r][4]);
                    acc[r][5] = fmaf(xv, wB.y, acc[r][5]);
                    acc[r][6] = fmaf(xv, wB.z, acc[r][6]);
                    acc[r][7] = fmaf(xv, wB.w, acc[r][7]);
                }
            }
        }
        __syncthreads();
    }

    float a1r[8], a2r[8];
#pragma unroll
    for (int c = 0; c < 4; ++c) {
        a1r[c]     = asrc[cA + c];  a2r[c]     = adst[cA + c];
        a1r[c + 4] = asrc[cB + c];  a2r[c + 4] = adst[cB + c];
    }

#pragma unroll
    for (int r = 0; r < 4; ++r) {
        int row = row0 + r;
        if (row < nrows) {
            int wA = __builtin_amdgcn_cvt_pk_fp8_f32(acc[r][0], acc[r][1], 0, false);
            wA     = __builtin_amdgcn_cvt_pk_fp8_f32(acc[r][2], acc[r][3], wA, true);
            int wB = __builtin_amdgcn_cvt_pk_fp8_f32(acc[r][4], acc[r][5], 0, false);
            wB     = __builtin_amdgcn_cvt_pk_fp8_f32(acc[r][6], acc[r][7], wB, true);
            Hb[(size_t)row * 32 + tx]      = (uint)wA;   // cols tx*4..+3
            Hb[(size_t)row * 32 + 16 + tx] = (uint)wB;   // cols 64+tx*4..+3
        }
        float p1 = 0.f, p2 = 0.f;
#pragma unroll
        for (int c = 0; c < 8; ++c) { p1 = fmaf(acc[r][c], a1r[c], p1); p2 = fmaf(acc[r][c], a2r[c], p2); }
#pragma unroll
        for (int m = 1; m < 16; m <<= 1) { p1 += __shfl_xor(p1, m); p2 += __shfl_xor(p2, m); }
        if (tx == 0 && row < nrows) { s1[row] = p1; s2[row] = p2; }
    }
}

// ---------- fused softmax + aggregation: one wave per EIGHT dst nodes ----------
__global__ __launch_bounds__(256) void agg_kernel(
    const ushort* __restrict__ Hb16, const int* __restrict__ csr_src,
    const int* __restrict__ row_ptr, const float* __restrict__ s1,
    const float* __restrict__ s2n, const float* __restrict__ bias,
    float2* __restrict__ Xout2, const int* __restrict__ batch,
    float* __restrict__ pooled, int pool_flag, int ngroups) {
    int gw = (blockIdx.x * blockDim.x + threadIdx.x) >> 6;
    int lane = threadIdx.x & 63;
    if (gw >= ngroups) return;
    int node0 = gw * 8;

    int4 rpa = *(const int4*)&row_ptr[node0];
    int4 rpb = *(const int4*)&row_ptr[node0 + 4];
    int rp8 = row_ptr[node0 + 8];
    int rp[9] = {rpa.x, rpa.y, rpa.z, rpa.w, rpb.x, rpb.y, rpb.z, rpb.w, rp8};
    float4 s2qa = *(const float4*)&s2n[node0];
    float4 s2qb = *(const float4*)&s2n[node0 + 4];
    float s2a[8] = {s2qa.x, s2qa.y, s2qa.z, s2qa.w, s2qb.x, s2qb.y, s2qb.z, s2qb.w};
    float2 b2 = ((const float2*)bias)[lane];
    int ba[8] = {0, 0, 0, 0, 0, 0, 0, 0};
    if (pool_flag) {
        int4 bqa = *(const int4*)&batch[node0];
        int4 bqb = *(const int4*)&batch[node0 + 4];
        ba[0] = bqa.x; ba[1] = bqa.y; ba[2] = bqa.z; ba[3] = bqa.w;
        ba[4] = bqb.x; ba[5] = bqb.y; ba[6] = bqb.z; ba[7] = bqb.w;
    }

#pragma unroll
    for (int k = 0; k < 8; ++k) {
        int beg = rp[k], end = rp[k + 1];
        float s2v = s2a[k];
        float2 acc = make_float2(0.f, 0.f);
        float wsum = 0.f;

        for (int s = beg; s < end; s += 8) {
            int4 a = *(const int4*)&csr_src[s];
            bool vb = (s + 4) < end;                     // wave-uniform
            int4 b = vb ? *(const int4*)&csr_src[s + 4] : make_int4(-1, -1, -1, -1);
            int sn[8] = {a.x, a.y, a.z, a.w, b.x, b.y, b.z, b.w};
            ushort hv[8];
#pragma unroll
            for (int j = 0; j < 8; ++j) {
                int r = (sn[j] < 0) ? 0 : sn[j];
                hv[j] = Hb16[(size_t)r * 64 + lane];
            }
            float w[8];
#pragma unroll
            for (int j = 0; j < 8; ++j) {
                int r = (sn[j] < 0) ? 0 : sn[j];
                float al = s1[r] + s2v;
                al = (al > 0.f) ? al : NEG_SLOPE * al;
                float e = __expf(al);
                w[j] = (sn[j] < 0) ? 0.f : e;
                wsum += w[j];
            }
#pragma unroll
            for (int j = 0; j < 8; ++j) {
                v2f f = __builtin_amdgcn_cvt_pk_f32_fp8((int)hv[j], false);
                acc.x = fmaf(w[j], f.x, acc.x);
                acc.y = fmaf(w[j], f.y, acc.y);
            }
        }

        float inv = 1.f / (wsum + 1e-16f);
        acc.x = fmaxf(fmaf(acc.x, inv, b2.x), 0.f);
        acc.y = fmaxf(fmaf(acc.y, inv, b2.y), 0.f);
        if (pool_flag) {
            atomicAdd(&pooled[ba[k] * DIM + 2 * lane], acc.x);
            atomicAdd(&pooled[ba[k] * DIM + 2 * lane + 1], acc.y);
        } else {
            Xout2[(size_t)(node0 + k) * 64 + lane] = acc;
        }
    }
}

__global__ void final_kernel(const float* __restrict__ pooled, const float* __restrict__ Wf,
                             const float* __restrict__ bf, float* __restrict__ y) {
    int wid = (blockIdx.x * blockDim.x + threadIdx.x) >> 6;
    int lane = threadIdx.x & 63;
    if (wid >= N_GRAPHS) return;
    float2 p = *(const float2*)&pooled[wid * DIM + 2 * lane];
    float2 w = *(const float2*)&Wf[2 * lane];
    float v = p.x * w.x + p.y * w.y;
    for (int off = 32; off; off >>= 1) v += __shfl_down(v, off);
    if (lane == 0) y[wid] = v + bf[0];
}

extern "C" void kernel_launch(void* const* d_in, const int* in_sizes, int n_in,
                              void* d_out, int out_size, void* d_ws, size_t ws_size,
                              hipStream_t stream) {
    const float* x       = (const float*)d_in[0];
    const int*   ei      = (const int*)d_in[1];
    const int*   batch   = (const int*)d_in[2];
    const float* Ws      = (const float*)d_in[3];
    const float* att_src = (const float*)d_in[4];
    const float* att_dst = (const float*)d_in[5];
    const float* biases  = (const float*)d_in[6];
    const float* Wf      = (const float*)d_in[7];
    const float* bf      = (const float*)d_in[8];
    float* y = (float*)d_out;

    char* p = (char*)d_ws;
    auto alloc = [&](size_t bytes) -> void* {
        void* r = (void*)p;
        p += (bytes + 255) & ~(size_t)255;
        return r;
    };
    float* xA      = (float*)alloc((size_t)N_NODES * DIM * 4);
    float* xB      = (float*)alloc((size_t)N_NODES * DIM * 4);
    uint*  Hb      = (uint*)alloc((size_t)N_NODES * 32 * 4);   // fp8 e4m3, 128 B/row
    int*   csr_src = (int*)alloc((size_t)E_CAP * 4);
    int*   deg     = (int*)alloc((size_t)N_NODES * 4);
    int*   fillc   = (int*)alloc((size_t)N_NODES * 4);
    int*   row_ptr = (int*)alloc((size_t)(N_NODES + 16) * 4);
    int*   blksum  = (int*)alloc(256 * 4);
    float* s1      = (float*)alloc((size_t)N_NODES * 4);
    float* s2      = (float*)alloc((size_t)(N_NODES + 8) * 4);
    float* pooled  = (float*)alloc((size_t)N_GRAPHS * DIM * 4);

    const int BN = 256;
    const int gN   = (N_NODES + BN - 1) / BN;
    const int gE   = (E_TOT + BN - 1) / BN;
    const int ngroups = N_NODES / 8;                 // 6250, exact
    const int gAGG = (ngroups * 64 + BN - 1) / BN;   // one wave per 8 nodes
    const int nblk = gN;

    init_kernel<<<gN, BN, 0, stream>>>(deg, fillc, pooled);
    count_kernel<<<gE, BN, 0, stream>>>(ei, deg);
    scan1_kernel<<<nblk, BN, 0, stream>>>(deg, row_ptr, blksum, N_NODES);
    scan2_kernel<<<1, BN, 0, stream>>>(blksum, row_ptr, nblk);
    scan3_kernel<<<gN, BN, 0, stream>>>(row_ptr, blksum, N_NODES);
    pad_kernel<<<gN, BN, 0, stream>>>(deg, row_ptr, csr_src);
    fill_kernel<<<gE, BN, 0, stream>>>(ei, row_ptr, fillc, csr_src);

    const float* xin = x;
    float* xout = xA;
    for (int l = 0; l < 3; ++l) {
        const float* W  = Ws + (size_t)l * DIM * DIM;
        const float* as = att_src + (size_t)l * DIM;
        const float* ad = att_dst + (size_t)l * DIM;
        const float* b  = biases + (size_t)l * DIM;

        gemm_dots_kernel<<<(N_NODES + 63) / 64, BN, 0, stream>>>(xin, W, as, ad, Hb, s1, s2, N_NODES);
        agg_kernel<<<gAGG, BN, 0, stream>>>((const ushort*)Hb, csr_src, row_ptr, s1, s2, b,
                                            (float2*)xout, batch, pooled,
                                            (l == 2) ? 1 : 0, ngroups);
        xin = xout;
        xout = (l == 0) ? xB : xA;
    }

    final_kernel<<<(N_GRAPHS * 64 + BN - 1) / BN, BN, 0, stream>>>(pooled, Wf, bf, y);
    (void)ws_size; (void)n_in; (void)in_sizes; (void)out_size;
}